// Round 13
// baseline (530.911 us; speedup 1.0000x reference)
//
#include <hip/hip_runtime.h>
#include <hip/hip_bf16.h>

// N=50000, E=800000, F=256
// x:[N,256] ei:[2,E] W1:[256,128] b1:[128] W2:[128,12] b2:[12]
// L1:[12,512] lb1:[512] L2:[512,512] lb2:[512] L3:[512,2] lb3:[2]
// out:[N,2] fp32

typedef short short8 __attribute__((ext_vector_type(8)));
typedef float f32x4 __attribute__((ext_vector_type(4)));

static __device__ __forceinline__ unsigned short f2bf(float f) {
    unsigned int u = __float_as_uint(f);
    u = (u + 0x7FFF + ((u >> 16) & 1)) >> 16;   // round-to-nearest-even
    return (unsigned short)u;
}
static __device__ __forceinline__ float bf2f(unsigned short s) {
    return __uint_as_float((unsigned int)s << 16);
}

// ---------------- CSR build ----------------
__global__ void k_init(int* __restrict__ deg, int* __restrict__ cursor, int n) {
    int i = blockIdx.x * blockDim.x + threadIdx.x;
    if (i < n) { deg[i] = 0; cursor[i] = 0; }
}

__global__ void k_count(const int* __restrict__ col, int* __restrict__ deg, int e) {
    int i = blockIdx.x * blockDim.x + threadIdx.x;
    if (i < e) atomicAdd(&deg[col[i]], 1);
}

__global__ void k_dinv(const int* __restrict__ deg, float* __restrict__ dinv, int n) {
    int i = blockIdx.x * blockDim.x + threadIdx.x;
    if (i < n) dinv[i] = 1.0f / sqrtf((float)deg[i] + 1.0f);  // +1 self-loop
}

// ---------------- two-level scan ----------------
__global__ __launch_bounds__(256)
void k_scanA(const int* __restrict__ deg, int* __restrict__ bsum, int n) {
    __shared__ int s[256];
    const int b = blockIdx.x, t = threadIdx.x;
    const int i = b * 256 + t;
    s[t] = (i < n) ? deg[i] : 0;
    __syncthreads();
    for (int d = 128; d; d >>= 1) {
        if (t < d) s[t] += s[t + d];
        __syncthreads();
    }
    if (t == 0) bsum[b] = s[0];
}

__global__ __launch_bounds__(1024)
void k_scanB(const int* __restrict__ bsum, int* __restrict__ boff, int nb) {
    __shared__ int s[1024];
    const int t = threadIdx.x;
    s[t] = (t < nb) ? bsum[t] : 0;
    __syncthreads();
    for (int d = 1; d < 1024; d <<= 1) {
        int v = (t >= d) ? s[t - d] : 0;
        __syncthreads();
        s[t] += v;
        __syncthreads();
    }
    if (t < nb) boff[t] = (t == 0) ? 0 : s[t - 1];   // exclusive
}

__global__ __launch_bounds__(256)
void k_scanC(const int* __restrict__ deg, const int* __restrict__ boff,
             int* __restrict__ off, int n) {
    __shared__ int s[256];
    const int b = blockIdx.x, t = threadIdx.x;
    const int i = b * 256 + t;
    const int v = (i < n) ? deg[i] : 0;
    s[t] = v;
    __syncthreads();
    for (int d = 1; d < 256; d <<= 1) {
        int u = (t >= d) ? s[t - d] : 0;
        __syncthreads();
        s[t] += u;
        __syncthreads();
    }
    if (i < n) off[i] = boff[b] + s[t] - v;
}

__global__ void k_fill(const int* __restrict__ row, const int* __restrict__ col,
                       const int* __restrict__ off, int* __restrict__ cursor,
                       int* __restrict__ nbr, int e) {
    int i = blockIdx.x * blockDim.x + threadIdx.x;
    if (i < e) {
        int c = col[i];
        int p = atomicAdd(&cursor[c], 1);
        nbr[off[c] + p] = row[i];
    }
}

// ---------------- L2 -> transposed bf16 hi/lo split (k-contiguous per col) ----------------
__global__ void k_cvtL2(const float* __restrict__ L2w,
                        short* __restrict__ L2hi, short* __restrict__ L2lo) {
    int col = blockIdx.x;   // 512 blocks
    for (int k = threadIdx.x; k < 512; k += 256) {
        float v = L2w[(size_t)k * 512 + col];
        unsigned short hb = f2bf(v);
        float hf = bf2f(hb);
        unsigned short lb = f2bf(v - hf);
        L2hi[(size_t)col * 512 + k] = (short)hb;
        L2lo[(size_t)col * 512 + k] = (short)lb;
    }
}

// ---------------- W1 -> transposed bf16 hi/lo split (k-contiguous per col) ----------------
__global__ void k_cvtW1(const float* __restrict__ W1,
                        short* __restrict__ W1hi, short* __restrict__ W1lo) {
    int col = blockIdx.x;   // 128 blocks
    for (int k = threadIdx.x; k < 256; k += 256) {
        float v = W1[(size_t)k * 128 + col];
        unsigned short hb = f2bf(v);
        float hf = bf2f(hb);
        unsigned short lb = f2bf(v - hf);
        W1hi[(size_t)col * 256 + k] = (short)hb;
        W1lo[(size_t)col * 256 + k] = (short)lb;
    }
}

// ---------------- GEMM1 (MFMA): t1s = (x @ W1) * dinv[r] ----------------
__global__ __launch_bounds__(256)
void k_gemm1(const float* __restrict__ x, const short* __restrict__ W1hi,
             const short* __restrict__ W1lo, const float* __restrict__ dinv,
             float* __restrict__ t1s, int M) {
    __shared__ short Ahi[64 * 32], Alo[64 * 32];       // [row][32k], swizzled 16B slots
    __shared__ short Bhi[128 * 32], Blo[128 * 32];     // [col][32k], swizzled
    const int t = threadIdx.x, lane = t & 63, wid = t >> 6;
    const int rb = blockIdx.x * 64;
    const int wr = wid >> 1, wc = wid & 1;              // wave = 32 rows x 64 cols

    f32x4 acc[2][4];
#pragma unroll
    for (int mt = 0; mt < 2; ++mt)
#pragma unroll
        for (int f = 0; f < 4; ++f) acc[mt][f] = 0.f;

    // staging assignments
    const int srow = t >> 2, skp = t & 3;       // A: 64 rows x 4 slots (8 floats)
    const int bcol = t >> 1, bkp = t & 1;       // B: 128 cols x 2 halves (16 shorts)
    const bool arv = (rb + srow) < M;
    const float* apx = x + (size_t)(rb + srow) * 256 + skp * 8;
    const short* bph = W1hi + (size_t)bcol * 256 + bkp * 16;
    const short* bpl = W1lo + (size_t)bcol * 256 + bkp * 16;

    // LDS byte offsets (swizzle: slot = k16 ^ (row&3) ^ ((row>>2)&1))
    const int aslot = skp ^ (srow & 3) ^ ((srow >> 2) & 1);
    const int aoff  = srow * 64 + aslot * 16;
    int boff[2];
#pragma unroll
    for (int i = 0; i < 2; ++i) {
        int k16 = bkp * 2 + i;
        int s = k16 ^ (bcol & 3) ^ ((bcol >> 2) & 1);
        boff[i] = bcol * 64 + s * 16;
    }

    float4 sax = make_float4(0.f, 0.f, 0.f, 0.f), say = sax;
    if (arv) { sax = ((const float4*)apx)[0]; say = ((const float4*)apx)[1]; }
    short8 sbh[2], sbl[2];
#pragma unroll
    for (int i = 0; i < 2; ++i) {
        sbh[i] = *(const short8*)(bph + i * 8);
        sbl[i] = *(const short8*)(bpl + i * 8);
    }

    for (int kc = 0; kc < 8; ++kc) {
        // split staged A f32 -> hi/lo, write LDS
        {
            float fv[8] = {sax.x, sax.y, sax.z, sax.w, say.x, say.y, say.z, say.w};
            short8 hv, lv;
#pragma unroll
            for (int e = 0; e < 8; ++e) {
                unsigned short hb = f2bf(fv[e]);
                float hf = bf2f(hb);
                unsigned short lb = f2bf(fv[e] - hf);
                hv[e] = (short)hb; lv[e] = (short)lb;
            }
            *(short8*)((char*)Ahi + aoff) = hv;
            *(short8*)((char*)Alo + aoff) = lv;
        }
#pragma unroll
        for (int i = 0; i < 2; ++i) {
            *(short8*)((char*)Bhi + boff[i]) = sbh[i];
            *(short8*)((char*)Blo + boff[i]) = sbl[i];
        }
        __syncthreads();
        if (kc < 7) {                        // T14: issue next chunk under MFMAs
            const int ko = (kc + 1) * 32;
            if (arv) {
                sax = ((const float4*)(apx + ko))[0];
                say = ((const float4*)(apx + ko))[1];
            }
#pragma unroll
            for (int i = 0; i < 2; ++i) {
                sbh[i] = *(const short8*)(bph + ko + i * 8);
                sbl[i] = *(const short8*)(bpl + ko + i * 8);
            }
        }
        // fragments
        const int g = lane >> 4;
        short8 ah[2], al[2];
#pragma unroll
        for (int mt = 0; mt < 2; ++mt) {
            int row = wr * 32 + mt * 16 + (lane & 15);
            int s = g ^ (row & 3) ^ ((row >> 2) & 1);
            int bo = row * 64 + s * 16;
            ah[mt] = *(const short8*)((const char*)Ahi + bo);
            al[mt] = *(const short8*)((const char*)Alo + bo);
        }
        short8 bh[4], bl[4];
#pragma unroll
        for (int f = 0; f < 4; ++f) {
            int col = wc * 64 + f * 16 + (lane & 15);
            int s = g ^ (col & 3) ^ ((col >> 2) & 1);
            int bo = col * 64 + s * 16;
            bh[f] = *(const short8*)((const char*)Bhi + bo);
            bl[f] = *(const short8*)((const char*)Blo + bo);
        }
#pragma unroll
        for (int f = 0; f < 4; ++f) {
#pragma unroll
            for (int mt = 0; mt < 2; ++mt) {
                f32x4 a = acc[mt][f];
                a = __builtin_amdgcn_mfma_f32_16x16x32_bf16(ah[mt], bh[f], a, 0, 0, 0);
                a = __builtin_amdgcn_mfma_f32_16x16x32_bf16(al[mt], bh[f], a, 0, 0, 0);
                a = __builtin_amdgcn_mfma_f32_16x16x32_bf16(ah[mt], bl[f], a, 0, 0, 0);
                acc[mt][f] = a;
            }
        }
        __syncthreads();
    }

    // epilogue: t1s[row][col] = acc * dinv[row]
    const int g = lane >> 4, c15 = lane & 15;
#pragma unroll
    for (int mt = 0; mt < 2; ++mt) {
#pragma unroll
        for (int r2 = 0; r2 < 4; ++r2) {
            int row = rb + wr * 32 + mt * 16 + g * 4 + r2;
            if (row < M) {
                float dv = dinv[row];
                float* op = t1s + (size_t)row * 128 + wc * 64 + c15;
#pragma unroll
                for (int f = 0; f < 4; ++f)
                    op[f * 16] = acc[mt][f][r2] * dv;
            }
        }
    }
}

// ---------------- gather1 + h1 epilogue ----------------
__global__ __launch_bounds__(256)
void k_gather1(const int* __restrict__ deg, const int* __restrict__ off,
               const int* __restrict__ nbr, const float* __restrict__ t1s,
               const float* __restrict__ dinv, const float* __restrict__ b1,
               float* __restrict__ h1, int n) {
    const int lane = threadIdx.x & 63;
    const int node = blockIdx.x * 4 + (threadIdx.x >> 6);
    if (node >= n) return;
    const int dg = deg[node];
    const int o  = off[node];
    const int f0 = lane * 2;
    float2 acc = *(const float2*)(t1s + (size_t)node * 128 + f0);  // self-loop
    int i = 0;
    for (; i + 4 <= dg; i += 4) {
        int r0 = nbr[o + i], r1 = nbr[o + i + 1], r2 = nbr[o + i + 2], r3 = nbr[o + i + 3];
        float2 a0 = *(const float2*)(t1s + (size_t)r0 * 128 + f0);
        float2 a1 = *(const float2*)(t1s + (size_t)r1 * 128 + f0);
        float2 a2 = *(const float2*)(t1s + (size_t)r2 * 128 + f0);
        float2 a3 = *(const float2*)(t1s + (size_t)r3 * 128 + f0);
        acc.x += a0.x + a1.x + a2.x + a3.x;
        acc.y += a0.y + a1.y + a2.y + a3.y;
    }
    for (; i < dg; ++i) {
        int r = nbr[o + i];
        float2 a = *(const float2*)(t1s + (size_t)r * 128 + f0);
        acc.x += a.x; acc.y += a.y;
    }
    float dv = dinv[node];
    float2 b = *(const float2*)(b1 + f0);
    float2 hv;
    hv.x = fmaxf(fmaf(acc.x, dv, b.x), 0.f);
    hv.y = fmaxf(fmaf(acc.y, dv, b.y), 0.f);
    *(float2*)(h1 + (size_t)node * 128 + f0) = hv;
}

// ---------------- GEMM2: t2s = (h1 @ W2) * dinv ----------------
__global__ __launch_bounds__(256)
void k_gemm2(const float* __restrict__ h1, const float* __restrict__ W2,
             const float* __restrict__ dinv, float* __restrict__ t2s, int n) {
    __shared__ float ws[128 * 12];
    int t = threadIdx.x;
    for (int i = t; i < 128 * 12; i += 256) ws[i] = W2[i];
    __syncthreads();
    int node = blockIdx.x * 256 + t;
    if (node >= n) return;
    const float4* hp = (const float4*)(h1 + (size_t)node * 128);
    float acc[12] = {};
    for (int k4 = 0; k4 < 32; ++k4) {
        float4 hv = hp[k4];
        float h[4] = {hv.x, hv.y, hv.z, hv.w};
#pragma unroll
        for (int q = 0; q < 4; ++q) {
            int k = k4 * 4 + q;
#pragma unroll
            for (int j = 0; j < 12; ++j)
                acc[j] = fmaf(h[q], ws[k * 12 + j], acc[j]);
        }
    }
    float dv = dinv[node];
    float* p1 = t2s + (size_t)node * 12;
#pragma unroll
    for (int j = 0; j < 12; ++j) p1[j] = acc[j] * dv;
}

// ---------------- out init: out[i] = lb3[i&1] ----------------
__global__ void k_outinit(float* __restrict__ out, const float* __restrict__ lb3, int n2) {
    int i = blockIdx.x * blockDim.x + threadIdx.x;
    if (i < n2) out[i] = lb3[i & 1];
}

// ---------------- k_h3: gather2+h2 -> h3 = relu(h2 @ L1 + lb1) -> bf16 hi/lo ----------------
__global__ __launch_bounds__(256)
void k_h3(const int* __restrict__ deg, const int* __restrict__ off,
          const int* __restrict__ nbr, const float* __restrict__ t2s,
          const float* __restrict__ dinv, const float* __restrict__ b2,
          const float* __restrict__ L1, const float* __restrict__ lb1,
          short* __restrict__ h3hi, short* __restrict__ h3lo, int base, int mh) {
    __shared__ float h2s[16][13];
    const int t  = threadIdx.x;
    const int nb = blockIdx.x * 16;     // local row base

    // phase A: gather2 + h2
    if (t < 192) {
        int ni = t / 12, j = t - ni * 12;
        int nl = nb + ni;
        float v = 0.f;
        if (nl < mh) {
            int node = base + nl;
            int dg = deg[node], o = off[node];
            float acc = t2s[(size_t)node * 12 + j];   // self-loop
            int i = 0;
            for (; i + 4 <= dg; i += 4) {
                int r0 = nbr[o + i], r1 = nbr[o + i + 1];
                int r2 = nbr[o + i + 2], r3 = nbr[o + i + 3];
                float a0 = t2s[(size_t)r0 * 12 + j], a1 = t2s[(size_t)r1 * 12 + j];
                float a2 = t2s[(size_t)r2 * 12 + j], a3 = t2s[(size_t)r3 * 12 + j];
                acc += (a0 + a1) + (a2 + a3);
            }
            for (; i < dg; ++i) acc += t2s[(size_t)nbr[o + i] * 12 + j];
            v = fmaxf(fmaf(acc, dinv[node], b2[j]), 0.f);
        }
        h2s[ni][j] = v;
    }
    __syncthreads();

    // phase B: 16 threads per node, each 4 chunks of 8 cols (stride-128)
    const int nloc = t >> 4, jg = t & 15;
    const int nl = nb + nloc;
    float h2r[12];
#pragma unroll
    for (int q = 0; q < 12; ++q) h2r[q] = h2s[nloc][q];
    if (nl < mh) {
        short* ophi = h3hi + (size_t)nl * 512;
        short* oplo = h3lo + (size_t)nl * 512;
#pragma unroll
        for (int i8 = 0; i8 < 4; ++i8) {
            int j0 = i8 * 128 + jg * 8;
            float4 a0 = *(const float4*)(lb1 + j0);
            float4 a1 = *(const float4*)(lb1 + j0 + 4);
            float v[8] = {a0.x, a0.y, a0.z, a0.w, a1.x, a1.y, a1.z, a1.w};
#pragma unroll
            for (int q = 0; q < 12; ++q) {
                float4 w0 = *(const float4*)(L1 + q * 512 + j0);
                float4 w1 = *(const float4*)(L1 + q * 512 + j0 + 4);
                float hq = h2r[q];
                v[0] = fmaf(hq, w0.x, v[0]); v[1] = fmaf(hq, w0.y, v[1]);
                v[2] = fmaf(hq, w0.z, v[2]); v[3] = fmaf(hq, w0.w, v[3]);
                v[4] = fmaf(hq, w1.x, v[4]); v[5] = fmaf(hq, w1.y, v[5]);
                v[6] = fmaf(hq, w1.z, v[6]); v[7] = fmaf(hq, w1.w, v[7]);
            }
            short8 hv, lv;
#pragma unroll
            for (int e = 0; e < 8; ++e) {
                float f = fmaxf(v[e], 0.f);
                unsigned short hb = f2bf(f);
                float hf = bf2f(hb);
                unsigned short lb = f2bf(f - hf);
                hv[e] = (short)hb; lv[e] = (short)lb;
            }
            *(short8*)(ophi + j0) = hv;
            *(short8*)(oplo + j0) = lv;
        }
    }
}

// ---------------- k_gemmL2 v3: BM=128/BN=128, kc=32, A+B in LDS, reg-prefetch ----------------
// Round-12 lesson: BM=64 gave only 24 MFMA/wave between barriers (MfmaUtil 24%).
// BM=128 doubles MFMA/barrier (48/wave) and halves per-dispatch B L2 traffic.
// 256 thr (4 waves 2x2); wave = 64 rows x 64 cols; acc 16 f32x4 = 64 VGPR.
__global__ __launch_bounds__(256)
void k_gemmL2(const short* __restrict__ h3hi, const short* __restrict__ h3lo,
              const short* __restrict__ L2hi, const short* __restrict__ L2lo,
              const float* __restrict__ lb2, const float* __restrict__ L3,
              float* __restrict__ out, int base, int mh) {
    __shared__ short Ahi[128 * 32], Alo[128 * 32];     // [row][32k], swizzled 16B slots
    __shared__ short Bhi[128 * 32], Blo[128 * 32];     // [col][32k], swizzled
    const int t = threadIdx.x, lane = t & 63, wid = t >> 6;

    // bijective chunked XCD remap (m204): hardware bid%8 = XCD
    const int nwg = gridDim.x, bid = blockIdx.x;
    const int q = nwg >> 3, r = nwg & 7;
    const int xcd = bid & 7, loc = bid >> 3;
    const int wg = (xcd < r ? xcd * (q + 1) : r * (q + 1) + (xcd - r) * q) + loc;
    const int mtile = wg >> 2, cblk = wg & 3;
    const int rb = mtile * 128;
    const int wr = wid >> 1, wc = wid & 1;
    const int wcb = cblk * 128 + wc * 64;       // global col base of wave

    f32x4 acc[4][4];
#pragma unroll
    for (int mt = 0; mt < 4; ++mt)
#pragma unroll
        for (int f = 0; f < 4; ++f) acc[mt][f] = 0.f;

    // staging assignments (A and B both: 128 rows/cols x 2 16-short halves)
    const int arow = t >> 1, akp = t & 1;
    const int bcol = t >> 1, bkp = t & 1;
    const bool arv = (rb + arow) < mh;
    const short* aph = h3hi + (size_t)(rb + arow) * 512 + akp * 16;
    const short* apl = h3lo + (size_t)(rb + arow) * 512 + akp * 16;
    const short* bph = L2hi + (size_t)(cblk * 128 + bcol) * 512 + bkp * 16;
    const short* bpl = L2lo + (size_t)(cblk * 128 + bcol) * 512 + bkp * 16;
    const short8 zz = {0, 0, 0, 0, 0, 0, 0, 0};

    // LDS byte offsets (swizzle: slot = k16 ^ (row&3) ^ ((row>>2)&1))
    int aoff[2], boff[2];
#pragma unroll
    for (int i = 0; i < 2; ++i) {
        int k16a = akp * 2 + i;
        int sa = k16a ^ (arow & 3) ^ ((arow >> 2) & 1);
        aoff[i] = arow * 64 + sa * 16;
        int k16b = bkp * 2 + i;
        int sb = k16b ^ (bcol & 3) ^ ((bcol >> 2) & 1);
        boff[i] = bcol * 64 + sb * 16;
    }

    short8 sah[2], sal[2], sbh[2], sbl[2];
#pragma unroll
    for (int i = 0; i < 2; ++i) {
        sah[i] = arv ? *(const short8*)(aph + i * 8) : zz;
        sal[i] = arv ? *(const short8*)(apl + i * 8) : zz;
        sbh[i] = *(const short8*)(bph + i * 8);
        sbl[i] = *(const short8*)(bpl + i * 8);
    }

    for (int kc = 0; kc < 16; ++kc) {
#pragma unroll
        for (int i = 0; i < 2; ++i) {
            *(short8*)((char*)Ahi + aoff[i]) = sah[i];
            *(short8*)((char*)Alo + aoff[i]) = sal[i];
            *(short8*)((char*)Bhi + boff[i]) = sbh[i];
            *(short8*)((char*)Blo + boff[i]) = sbl[i];
        }
        __syncthreads();
        if (kc < 15) {                       // T14: issue next chunk under MFMAs
            const int ko = (kc + 1) * 32;
#pragma unroll
            for (int i = 0; i < 2; ++i) {
                sah[i] = arv ? *(const short8*)(aph + ko + i * 8) : zz;
                sal[i] = arv ? *(const short8*)(apl + ko + i * 8) : zz;
                sbh[i] = *(const short8*)(bph + ko + i * 8);
                sbl[i] = *(const short8*)(bpl + ko + i * 8);
            }
        }
        // fragments
        const int g = lane >> 4;
        short8 bh[4], bl[4];
#pragma unroll
        for (int f = 0; f < 4; ++f) {
            int col = wc * 64 + f * 16 + (lane & 15);
            int s = g ^ (col & 3) ^ ((col >> 2) & 1);
            int bo = col * 64 + s * 16;
            bh[f] = *(const short8*)((const char*)Bhi + bo);
            bl[f] = *(const short8*)((const char*)Blo + bo);
        }
#pragma unroll
        for (int mt = 0; mt < 4; ++mt) {
            int row = wr * 64 + mt * 16 + (lane & 15);
            int s = g ^ (row & 3) ^ ((row >> 2) & 1);
            int bo = row * 64 + s * 16;
            short8 ah = *(const short8*)((const char*)Ahi + bo);
            short8 al = *(const short8*)((const char*)Alo + bo);
#pragma unroll
            for (int f = 0; f < 4; ++f) {
                f32x4 a = acc[mt][f];
                a = __builtin_amdgcn_mfma_f32_16x16x32_bf16(ah, bh[f], a, 0, 0, 0);
                a = __builtin_amdgcn_mfma_f32_16x16x32_bf16(al, bh[f], a, 0, 0, 0);
                a = __builtin_amdgcn_mfma_f32_16x16x32_bf16(ah, bl[f], a, 0, 0, 0);
                acc[mt][f] = a;
            }
        }
        __syncthreads();
    }

    // epilogue: h4 = relu(acc + lb2[col]); po += h4 * L3[col]; reduce over 16 col-lanes
    float po[4][4][2];
#pragma unroll
    for (int mt = 0; mt < 4; ++mt)
#pragma unroll
        for (int r2 = 0; r2 < 4; ++r2) { po[mt][r2][0] = 0.f; po[mt][r2][1] = 0.f; }
#pragma unroll
    for (int f = 0; f < 4; ++f) {
        int col = wcb + f * 16 + (lane & 15);
        float bb = lb2[col];
        float2 l3 = *(const float2*)(L3 + (size_t)col * 2);
#pragma unroll
        for (int mt = 0; mt < 4; ++mt)
#pragma unroll
            for (int r2 = 0; r2 < 4; ++r2) {
                float h4 = fmaxf(acc[mt][f][r2] + bb, 0.f);
                po[mt][r2][0] = fmaf(h4, l3.x, po[mt][r2][0]);
                po[mt][r2][1] = fmaf(h4, l3.y, po[mt][r2][1]);
            }
    }
#pragma unroll
    for (int ofs = 1; ofs <= 8; ofs <<= 1) {
#pragma unroll
        for (int mt = 0; mt < 4; ++mt)
#pragma unroll
            for (int r2 = 0; r2 < 4; ++r2) {
                po[mt][r2][0] += __shfl_xor(po[mt][r2][0], ofs, 64);
                po[mt][r2][1] += __shfl_xor(po[mt][r2][1], ofs, 64);
            }
    }
    if ((lane & 15) == 0) {
        const int g = lane >> 4;
#pragma unroll
        for (int mt = 0; mt < 4; ++mt)
#pragma unroll
            for (int r2 = 0; r2 < 4; ++r2) {
                int row_l = rb + wr * 64 + mt * 16 + g * 4 + r2;
                if (row_l < mh) {
                    atomicAdd(&out[(size_t)(base + row_l) * 2 + 0], po[mt][r2][0]);
                    atomicAdd(&out[(size_t)(base + row_l) * 2 + 1], po[mt][r2][1]);
                }
            }
    }
}

extern "C" void kernel_launch(void* const* d_in, const int* in_sizes, int n_in,
                              void* d_out, int out_size, void* d_ws, size_t ws_size,
                              hipStream_t stream) {
    const float* x   = (const float*)d_in[0];
    const int*   ei  = (const int*)d_in[1];
    const float* W1  = (const float*)d_in[2];
    const float* b1  = (const float*)d_in[3];
    const float* W2  = (const float*)d_in[4];
    const float* b2  = (const float*)d_in[5];
    const float* L1  = (const float*)d_in[6];
    const float* lb1 = (const float*)d_in[7];
    const float* L2w = (const float*)d_in[8];
    const float* lb2 = (const float*)d_in[9];
    const float* L3  = (const float*)d_in[10];
    const float* lb3 = (const float*)d_in[11];
    float* out = (float*)d_out;

    const int N = in_sizes[0] / 256;
    const int E = in_sizes[1] / 2;
    const int* rowp = ei;       // edge_index[0]
    const int* colp = ei + E;   // edge_index[1]

    const int mh0 = (N + 1) / 2;
    const int mh1 = N - mh0;
    const int nsb = (N + 255) / 256;                // scan blocks

    char* ws = (char*)d_ws;
    int*   deg    = (int*)ws;                       // N
    int*   cursor = deg + N;                        // N
    int*   offp   = cursor + N;                     // N
    float* dinv   = (float*)(offp + N);             // N
    int*   bsum   = (int*)(dinv + N);               // nsb
    int*   boffb  = bsum + 1024;                    // nsb (1024-padded)
    int*   nbr    = boffb + 1024;                   // E
    char*  bigbuf = (char*)(nbr + E);               // N*128*4*2 bytes, aliased
    float* t1s    = (float*)bigbuf;                 // N*128 floats
    float* h1     = t1s + (size_t)N * 128;          // N*128 floats
    short* h3hi   = (short*)bigbuf;                 // alias: mh*512 shorts (per half)
    short* h3lo   = h3hi + (size_t)mh0 * 512;       // alias
    float* t2s    = (float*)(bigbuf + (size_t)N * 128 * 4 * 2);   // N*12
    short* L2hi   = (short*)(t2s + (size_t)N * 12); // 512*512
    short* L2lo   = L2hi + 512 * 512;               // 512*512
    short* W1hi   = L2lo + 512 * 512;               // 256*128
    short* W1lo   = W1hi + 256 * 128;               // 256*128

    k_init  <<<(N + 255) / 256, 256, 0, stream>>>(deg, cursor, N);
    k_count <<<(E + 255) / 256, 256, 0, stream>>>(colp, deg, E);
    k_dinv  <<<(N + 255) / 256, 256, 0, stream>>>(deg, dinv, N);
    k_scanA <<<nsb, 256, 0, stream>>>(deg, bsum, N);
    k_scanB <<<1, 1024, 0, stream>>>(bsum, boffb, nsb);
    k_scanC <<<nsb, 256, 0, stream>>>(deg, boffb, offp, N);
    k_fill  <<<(E + 255) / 256, 256, 0, stream>>>(rowp, colp, offp, cursor, nbr, E);
    k_cvtL2 <<<512, 256, 0, stream>>>(L2w, L2hi, L2lo);
    k_cvtW1 <<<128, 256, 0, stream>>>(W1, W1hi, W1lo);

    k_gemm1   <<<(N + 63) / 64, 256, 0, stream>>>(x, W1hi, W1lo, dinv, t1s, N);
    k_gather1 <<<(N + 3) / 4, 256, 0, stream>>>(deg, offp, nbr, t1s, dinv, b1, h1, N);
    k_gemm2   <<<(N + 255) / 256, 256, 0, stream>>>(h1, W2, dinv, t2s, N);

    k_outinit <<<(2 * N + 255) / 256, 256, 0, stream>>>(out, lb3, 2 * N);

    int bases[2] = {0, mh0};
    int mhs[2]   = {mh0, mh1};
    for (int h = 0; h < 2; ++h) {
        int mh = mhs[h];
        if (mh <= 0) continue;
        int mt = (mh + 127) / 128;
        k_h3     <<<(mh + 15) / 16, 256, 0, stream>>>(deg, offp, nbr, t2s, dinv, b2,
                                                      L1, lb1, h3hi, h3lo, bases[h], mh);
        k_gemmL2 <<<mt * 4, 256, 0, stream>>>(h3hi, h3lo, L2hi, L2lo, lb2, L3,
                                              out, bases[h], mh);
    }
}

// Round 14
// 478.071 us; speedup vs baseline: 1.1105x; 1.1105x over previous
//
#include <hip/hip_runtime.h>
#include <hip/hip_bf16.h>

// N=50000, E=800000, F=256
// x:[N,256] ei:[2,E] W1:[256,128] b1:[128] W2:[128,12] b2:[12]
// L1:[12,512] lb1:[512] L2:[512,512] lb2:[512] L3:[512,2] lb3:[2]
// out:[N,2] fp32

typedef short short8 __attribute__((ext_vector_type(8)));
typedef float f32x4 __attribute__((ext_vector_type(4)));

static __device__ __forceinline__ unsigned short f2bf(float f) {
    unsigned int u = __float_as_uint(f);
    u = (u + 0x7FFF + ((u >> 16) & 1)) >> 16;   // round-to-nearest-even
    return (unsigned short)u;
}
static __device__ __forceinline__ float bf2f(unsigned short s) {
    return __uint_as_float((unsigned int)s << 16);
}

// ---------------- CSR build ----------------
__global__ void k_init(int* __restrict__ deg, int* __restrict__ cursor, int n) {
    int i = blockIdx.x * blockDim.x + threadIdx.x;
    if (i < n) { deg[i] = 0; cursor[i] = 0; }
}

__global__ void k_count(const int* __restrict__ col, int* __restrict__ deg, int e) {
    int i = blockIdx.x * blockDim.x + threadIdx.x;
    if (i < e) atomicAdd(&deg[col[i]], 1);
}

__global__ void k_dinv(const int* __restrict__ deg, float* __restrict__ dinv, int n) {
    int i = blockIdx.x * blockDim.x + threadIdx.x;
    if (i < n) dinv[i] = 1.0f / sqrtf((float)deg[i] + 1.0f);  // +1 self-loop
}

// ---------------- two-level scan ----------------
__global__ __launch_bounds__(256)
void k_scanA(const int* __restrict__ deg, int* __restrict__ bsum, int n) {
    __shared__ int s[256];
    const int b = blockIdx.x, t = threadIdx.x;
    const int i = b * 256 + t;
    s[t] = (i < n) ? deg[i] : 0;
    __syncthreads();
    for (int d = 128; d; d >>= 1) {
        if (t < d) s[t] += s[t + d];
        __syncthreads();
    }
    if (t == 0) bsum[b] = s[0];
}

__global__ __launch_bounds__(1024)
void k_scanB(const int* __restrict__ bsum, int* __restrict__ boff, int nb) {
    __shared__ int s[1024];
    const int t = threadIdx.x;
    s[t] = (t < nb) ? bsum[t] : 0;
    __syncthreads();
    for (int d = 1; d < 1024; d <<= 1) {
        int v = (t >= d) ? s[t - d] : 0;
        __syncthreads();
        s[t] += v;
        __syncthreads();
    }
    if (t < nb) boff[t] = (t == 0) ? 0 : s[t - 1];   // exclusive
}

__global__ __launch_bounds__(256)
void k_scanC(const int* __restrict__ deg, const int* __restrict__ boff,
             int* __restrict__ off, int n) {
    __shared__ int s[256];
    const int b = blockIdx.x, t = threadIdx.x;
    const int i = b * 256 + t;
    const int v = (i < n) ? deg[i] : 0;
    s[t] = v;
    __syncthreads();
    for (int d = 1; d < 256; d <<= 1) {
        int u = (t >= d) ? s[t - d] : 0;
        __syncthreads();
        s[t] += u;
        __syncthreads();
    }
    if (i < n) off[i] = boff[b] + s[t] - v;
}

__global__ void k_fill(const int* __restrict__ row, const int* __restrict__ col,
                       const int* __restrict__ off, int* __restrict__ cursor,
                       int* __restrict__ nbr, int e) {
    int i = blockIdx.x * blockDim.x + threadIdx.x;
    if (i < e) {
        int c = col[i];
        int p = atomicAdd(&cursor[c], 1);
        nbr[off[c] + p] = row[i];
    }
}

// ---------------- L2 -> transposed bf16 hi/lo split (k-contiguous per col) ----------------
__global__ void k_cvtL2(const float* __restrict__ L2w,
                        short* __restrict__ L2hi, short* __restrict__ L2lo) {
    int col = blockIdx.x;   // 512 blocks
    for (int k = threadIdx.x; k < 512; k += 256) {
        float v = L2w[(size_t)k * 512 + col];
        unsigned short hb = f2bf(v);
        float hf = bf2f(hb);
        unsigned short lb = f2bf(v - hf);
        L2hi[(size_t)col * 512 + k] = (short)hb;
        L2lo[(size_t)col * 512 + k] = (short)lb;
    }
}

// ---------------- W1 -> transposed bf16 hi/lo split (k-contiguous per col) ----------------
__global__ void k_cvtW1(const float* __restrict__ W1,
                        short* __restrict__ W1hi, short* __restrict__ W1lo) {
    int col = blockIdx.x;   // 128 blocks
    for (int k = threadIdx.x; k < 256; k += 256) {
        float v = W1[(size_t)k * 128 + col];
        unsigned short hb = f2bf(v);
        float hf = bf2f(hb);
        unsigned short lb = f2bf(v - hf);
        W1hi[(size_t)col * 256 + k] = (short)hb;
        W1lo[(size_t)col * 256 + k] = (short)lb;
    }
}

// ---------------- GEMM1 (MFMA): t1s = (x @ W1) * dinv[r] ----------------
__global__ __launch_bounds__(256)
void k_gemm1(const float* __restrict__ x, const short* __restrict__ W1hi,
             const short* __restrict__ W1lo, const float* __restrict__ dinv,
             float* __restrict__ t1s, int M) {
    __shared__ short Ahi[64 * 32], Alo[64 * 32];       // [row][32k], swizzled 16B slots
    __shared__ short Bhi[128 * 32], Blo[128 * 32];     // [col][32k], swizzled
    const int t = threadIdx.x, lane = t & 63, wid = t >> 6;
    const int rb = blockIdx.x * 64;
    const int wr = wid >> 1, wc = wid & 1;              // wave = 32 rows x 64 cols

    f32x4 acc[2][4];
#pragma unroll
    for (int mt = 0; mt < 2; ++mt)
#pragma unroll
        for (int f = 0; f < 4; ++f) acc[mt][f] = 0.f;

    // staging assignments
    const int srow = t >> 2, skp = t & 3;       // A: 64 rows x 4 slots (8 floats)
    const int bcol = t >> 1, bkp = t & 1;       // B: 128 cols x 2 halves (16 shorts)
    const bool arv = (rb + srow) < M;
    const float* apx = x + (size_t)(rb + srow) * 256 + skp * 8;
    const short* bph = W1hi + (size_t)bcol * 256 + bkp * 16;
    const short* bpl = W1lo + (size_t)bcol * 256 + bkp * 16;

    // LDS byte offsets (swizzle: slot = k16 ^ (row&3) ^ ((row>>2)&1))
    const int aslot = skp ^ (srow & 3) ^ ((srow >> 2) & 1);
    const int aoff  = srow * 64 + aslot * 16;
    int boff[2];
#pragma unroll
    for (int i = 0; i < 2; ++i) {
        int k16 = bkp * 2 + i;
        int s = k16 ^ (bcol & 3) ^ ((bcol >> 2) & 1);
        boff[i] = bcol * 64 + s * 16;
    }

    float4 sax = make_float4(0.f, 0.f, 0.f, 0.f), say = sax;
    if (arv) { sax = ((const float4*)apx)[0]; say = ((const float4*)apx)[1]; }
    short8 sbh[2], sbl[2];
#pragma unroll
    for (int i = 0; i < 2; ++i) {
        sbh[i] = *(const short8*)(bph + i * 8);
        sbl[i] = *(const short8*)(bpl + i * 8);
    }

    for (int kc = 0; kc < 8; ++kc) {
        // split staged A f32 -> hi/lo, write LDS
        {
            float fv[8] = {sax.x, sax.y, sax.z, sax.w, say.x, say.y, say.z, say.w};
            short8 hv, lv;
#pragma unroll
            for (int e = 0; e < 8; ++e) {
                unsigned short hb = f2bf(fv[e]);
                float hf = bf2f(hb);
                unsigned short lb = f2bf(fv[e] - hf);
                hv[e] = (short)hb; lv[e] = (short)lb;
            }
            *(short8*)((char*)Ahi + aoff) = hv;
            *(short8*)((char*)Alo + aoff) = lv;
        }
#pragma unroll
        for (int i = 0; i < 2; ++i) {
            *(short8*)((char*)Bhi + boff[i]) = sbh[i];
            *(short8*)((char*)Blo + boff[i]) = sbl[i];
        }
        __syncthreads();
        if (kc < 7) {                        // T14: issue next chunk under MFMAs
            const int ko = (kc + 1) * 32;
            if (arv) {
                sax = ((const float4*)(apx + ko))[0];
                say = ((const float4*)(apx + ko))[1];
            }
#pragma unroll
            for (int i = 0; i < 2; ++i) {
                sbh[i] = *(const short8*)(bph + ko + i * 8);
                sbl[i] = *(const short8*)(bpl + ko + i * 8);
            }
        }
        // fragments
        const int g = lane >> 4;
        short8 ah[2], al[2];
#pragma unroll
        for (int mt = 0; mt < 2; ++mt) {
            int row = wr * 32 + mt * 16 + (lane & 15);
            int s = g ^ (row & 3) ^ ((row >> 2) & 1);
            int bo = row * 64 + s * 16;
            ah[mt] = *(const short8*)((const char*)Ahi + bo);
            al[mt] = *(const short8*)((const char*)Alo + bo);
        }
        short8 bh[4], bl[4];
#pragma unroll
        for (int f = 0; f < 4; ++f) {
            int col = wc * 64 + f * 16 + (lane & 15);
            int s = g ^ (col & 3) ^ ((col >> 2) & 1);
            int bo = col * 64 + s * 16;
            bh[f] = *(const short8*)((const char*)Bhi + bo);
            bl[f] = *(const short8*)((const char*)Blo + bo);
        }
#pragma unroll
        for (int f = 0; f < 4; ++f) {
#pragma unroll
            for (int mt = 0; mt < 2; ++mt) {
                f32x4 a = acc[mt][f];
                a = __builtin_amdgcn_mfma_f32_16x16x32_bf16(ah[mt], bh[f], a, 0, 0, 0);
                a = __builtin_amdgcn_mfma_f32_16x16x32_bf16(al[mt], bh[f], a, 0, 0, 0);
                a = __builtin_amdgcn_mfma_f32_16x16x32_bf16(ah[mt], bl[f], a, 0, 0, 0);
                acc[mt][f] = a;
            }
        }
        __syncthreads();
    }

    // epilogue: t1s[row][col] = acc * dinv[row]
    const int g = lane >> 4, c15 = lane & 15;
#pragma unroll
    for (int mt = 0; mt < 2; ++mt) {
#pragma unroll
        for (int r2 = 0; r2 < 4; ++r2) {
            int row = rb + wr * 32 + mt * 16 + g * 4 + r2;
            if (row < M) {
                float dv = dinv[row];
                float* op = t1s + (size_t)row * 128 + wc * 64 + c15;
#pragma unroll
                for (int f = 0; f < 4; ++f)
                    op[f * 16] = acc[mt][f][r2] * dv;
            }
        }
    }
}

// ---------------- gather1 + h1 epilogue (float4, 2 neighbors per wave-iter) ----------------
// wave per node; lanes 0-31 handle even-indexed neighbors, 32-63 odd; lane covers
// 4 contiguous floats (16B coalescing sweet spot); final __shfl_xor(32) combine.
__global__ __launch_bounds__(256)
void k_gather1(const int* __restrict__ deg, const int* __restrict__ off,
               const int* __restrict__ nbr, const float* __restrict__ t1s,
               const float* __restrict__ dinv, const float* __restrict__ b1,
               float* __restrict__ h1, int n) {
    const int lane = threadIdx.x & 63;
    const int node = blockIdx.x * 4 + (threadIdx.x >> 6);
    if (node >= n) return;
    const int half = lane >> 5, l32 = lane & 31;
    const int f0 = l32 * 4;
    const int dg = deg[node];
    const int o  = off[node];

    float4 acc = make_float4(0.f, 0.f, 0.f, 0.f);
    if (half == 0)
        acc = *(const float4*)(t1s + (size_t)node * 128 + f0);   // self-loop
    int idx = half;
    for (; idx + 2 < dg; idx += 4) {     // 2 neighbors per pass per half
        int r0 = nbr[o + idx], r1 = nbr[o + idx + 2];
        float4 a0 = *(const float4*)(t1s + (size_t)r0 * 128 + f0);
        float4 a1 = *(const float4*)(t1s + (size_t)r1 * 128 + f0);
        acc.x += a0.x + a1.x; acc.y += a0.y + a1.y;
        acc.z += a0.z + a1.z; acc.w += a0.w + a1.w;
    }
    for (; idx < dg; idx += 2) {
        int r = nbr[o + idx];
        float4 a = *(const float4*)(t1s + (size_t)r * 128 + f0);
        acc.x += a.x; acc.y += a.y; acc.z += a.z; acc.w += a.w;
    }
    // combine halves
    acc.x += __shfl_xor(acc.x, 32, 64);
    acc.y += __shfl_xor(acc.y, 32, 64);
    acc.z += __shfl_xor(acc.z, 32, 64);
    acc.w += __shfl_xor(acc.w, 32, 64);
    if (half == 0) {
        float dv = dinv[node];
        float4 b = *(const float4*)(b1 + f0);
        float4 hv;
        hv.x = fmaxf(fmaf(acc.x, dv, b.x), 0.f);
        hv.y = fmaxf(fmaf(acc.y, dv, b.y), 0.f);
        hv.z = fmaxf(fmaf(acc.z, dv, b.z), 0.f);
        hv.w = fmaxf(fmaf(acc.w, dv, b.w), 0.f);
        *(float4*)(h1 + (size_t)node * 128 + f0) = hv;
    }
}

// ---------------- GEMM2: t2s = (h1 @ W2) * dinv ----------------
__global__ __launch_bounds__(256)
void k_gemm2(const float* __restrict__ h1, const float* __restrict__ W2,
             const float* __restrict__ dinv, float* __restrict__ t2s, int n) {
    __shared__ float ws[128 * 12];
    int t = threadIdx.x;
    for (int i = t; i < 128 * 12; i += 256) ws[i] = W2[i];
    __syncthreads();
    int node = blockIdx.x * 256 + t;
    if (node >= n) return;
    const float4* hp = (const float4*)(h1 + (size_t)node * 128);
    float acc[12] = {};
    for (int k4 = 0; k4 < 32; ++k4) {
        float4 hv = hp[k4];
        float h[4] = {hv.x, hv.y, hv.z, hv.w};
#pragma unroll
        for (int q = 0; q < 4; ++q) {
            int k = k4 * 4 + q;
#pragma unroll
            for (int j = 0; j < 12; ++j)
                acc[j] = fmaf(h[q], ws[k * 12 + j], acc[j]);
        }
    }
    float dv = dinv[node];
    float* p1 = t2s + (size_t)node * 12;
#pragma unroll
    for (int j = 0; j < 12; ++j) p1[j] = acc[j] * dv;
}

// ---------------- out init: out[i] = lb3[i&1] ----------------
__global__ void k_outinit(float* __restrict__ out, const float* __restrict__ lb3, int n2) {
    int i = blockIdx.x * blockDim.x + threadIdx.x;
    if (i < n2) out[i] = lb3[i & 1];
}

// ---------------- k_h3: gather2+h2 -> h3 = relu(h2 @ L1 + lb1) -> bf16 hi/lo ----------------
__global__ __launch_bounds__(256)
void k_h3(const int* __restrict__ deg, const int* __restrict__ off,
          const int* __restrict__ nbr, const float* __restrict__ t2s,
          const float* __restrict__ dinv, const float* __restrict__ b2,
          const float* __restrict__ L1, const float* __restrict__ lb1,
          short* __restrict__ h3hi, short* __restrict__ h3lo, int base, int mh) {
    __shared__ float h2s[16][13];
    const int t  = threadIdx.x;
    const int nb = blockIdx.x * 16;     // local row base

    // phase A: gather2 + h2
    if (t < 192) {
        int ni = t / 12, j = t - ni * 12;
        int nl = nb + ni;
        float v = 0.f;
        if (nl < mh) {
            int node = base + nl;
            int dg = deg[node], o = off[node];
            float acc = t2s[(size_t)node * 12 + j];   // self-loop
            int i = 0;
            for (; i + 4 <= dg; i += 4) {
                int r0 = nbr[o + i], r1 = nbr[o + i + 1];
                int r2 = nbr[o + i + 2], r3 = nbr[o + i + 3];
                float a0 = t2s[(size_t)r0 * 12 + j], a1 = t2s[(size_t)r1 * 12 + j];
                float a2 = t2s[(size_t)r2 * 12 + j], a3 = t2s[(size_t)r3 * 12 + j];
                acc += (a0 + a1) + (a2 + a3);
            }
            for (; i < dg; ++i) acc += t2s[(size_t)nbr[o + i] * 12 + j];
            v = fmaxf(fmaf(acc, dinv[node], b2[j]), 0.f);
        }
        h2s[ni][j] = v;
    }
    __syncthreads();

    // phase B: 16 threads per node, each 4 chunks of 8 cols (stride-128)
    const int nloc = t >> 4, jg = t & 15;
    const int nl = nb + nloc;
    float h2r[12];
#pragma unroll
    for (int q = 0; q < 12; ++q) h2r[q] = h2s[nloc][q];
    if (nl < mh) {
        short* ophi = h3hi + (size_t)nl * 512;
        short* oplo = h3lo + (size_t)nl * 512;
#pragma unroll
        for (int i8 = 0; i8 < 4; ++i8) {
            int j0 = i8 * 128 + jg * 8;
            float4 a0 = *(const float4*)(lb1 + j0);
            float4 a1 = *(const float4*)(lb1 + j0 + 4);
            float v[8] = {a0.x, a0.y, a0.z, a0.w, a1.x, a1.y, a1.z, a1.w};
#pragma unroll
            for (int q = 0; q < 12; ++q) {
                float4 w0 = *(const float4*)(L1 + q * 512 + j0);
                float4 w1 = *(const float4*)(L1 + q * 512 + j0 + 4);
                float hq = h2r[q];
                v[0] = fmaf(hq, w0.x, v[0]); v[1] = fmaf(hq, w0.y, v[1]);
                v[2] = fmaf(hq, w0.z, v[2]); v[3] = fmaf(hq, w0.w, v[3]);
                v[4] = fmaf(hq, w1.x, v[4]); v[5] = fmaf(hq, w1.y, v[5]);
                v[6] = fmaf(hq, w1.z, v[6]); v[7] = fmaf(hq, w1.w, v[7]);
            }
            short8 hv, lv;
#pragma unroll
            for (int e = 0; e < 8; ++e) {
                float f = fmaxf(v[e], 0.f);
                unsigned short hb = f2bf(f);
                float hf = bf2f(hb);
                unsigned short lb = f2bf(f - hf);
                hv[e] = (short)hb; lv[e] = (short)lb;
            }
            *(short8*)(ophi + j0) = hv;
            *(short8*)(oplo + j0) = lv;
        }
    }
}

// ---------------- k_gemmL2 v2 (round-12 verbatim): BM=64/BN=128, kc=32 ----------------
__global__ __launch_bounds__(256)
void k_gemmL2(const short* __restrict__ h3hi, const short* __restrict__ h3lo,
              const short* __restrict__ L2hi, const short* __restrict__ L2lo,
              const float* __restrict__ lb2, const float* __restrict__ L3,
              float* __restrict__ out, int base, int mh) {
    __shared__ short Ahi[64 * 32], Alo[64 * 32];       // [row][32k], swizzled 16B slots
    __shared__ short Bhi[128 * 32], Blo[128 * 32];     // [col][32k], swizzled
    const int t = threadIdx.x, lane = t & 63, wid = t >> 6;

    // bijective chunked XCD remap (m204): hardware bid%8 = XCD
    const int nwg = gridDim.x, bid = blockIdx.x;
    const int q = nwg >> 3, r = nwg & 7;
    const int xcd = bid & 7, loc = bid >> 3;
    const int wg = (xcd < r ? xcd * (q + 1) : r * (q + 1) + (xcd - r) * q) + loc;
    const int mtile = wg >> 2, cblk = wg & 3;
    const int rb = mtile * 64;
    const int wr = wid >> 1, wc = wid & 1;
    const int wcb = cblk * 128 + wc * 64;       // global col base of wave

    f32x4 acc[2][4];
#pragma unroll
    for (int mt = 0; mt < 2; ++mt)
#pragma unroll
        for (int f = 0; f < 4; ++f) acc[mt][f] = 0.f;

    // staging assignments
    const int srow = t >> 2, skp = t & 3;       // A: 64 rows x 4 8-short slots
    const int bcol = t >> 1, bkp = t & 1;       // B: 128 cols x 2 16-short halves
    const bool arv = (rb + srow) < mh;
    const short* aph = h3hi + (size_t)(rb + srow) * 512 + skp * 8;
    const short* apl = h3lo + (size_t)(rb + srow) * 512 + skp * 8;
    const short* bph = L2hi + (size_t)(cblk * 128 + bcol) * 512 + bkp * 16;
    const short* bpl = L2lo + (size_t)(cblk * 128 + bcol) * 512 + bkp * 16;
    const short8 zz = {0, 0, 0, 0, 0, 0, 0, 0};

    // LDS byte offsets (swizzle: slot = k16 ^ (row&3) ^ ((row>>2)&1))
    const int aslot = skp ^ (srow & 3) ^ ((srow >> 2) & 1);
    const int aoff  = srow * 64 + aslot * 16;
    int boff[2];
#pragma unroll
    for (int i = 0; i < 2; ++i) {
        int k16 = bkp * 2 + i;
        int s = k16 ^ (bcol & 3) ^ ((bcol >> 2) & 1);
        boff[i] = bcol * 64 + s * 16;
    }

    short8 sah, sal, sbh[2], sbl[2];
    sah = arv ? *(const short8*)(aph) : zz;
    sal = arv ? *(const short8*)(apl) : zz;
#pragma unroll
    for (int i = 0; i < 2; ++i) {
        sbh[i] = *(const short8*)(bph + i * 8);
        sbl[i] = *(const short8*)(bpl + i * 8);
    }

    for (int kc = 0; kc < 16; ++kc) {
        *(short8*)((char*)Ahi + aoff) = sah;
        *(short8*)((char*)Alo + aoff) = sal;
#pragma unroll
        for (int i = 0; i < 2; ++i) {
            *(short8*)((char*)Bhi + boff[i]) = sbh[i];
            *(short8*)((char*)Blo + boff[i]) = sbl[i];
        }
        __syncthreads();
        if (kc < 15) {                       // T14: issue next chunk under MFMAs
            const int ko = (kc + 1) * 32;
            sah = arv ? *(const short8*)(aph + ko) : zz;
            sal = arv ? *(const short8*)(apl + ko) : zz;
#pragma unroll
            for (int i = 0; i < 2; ++i) {
                sbh[i] = *(const short8*)(bph + ko + i * 8);
                sbl[i] = *(const short8*)(bpl + ko + i * 8);
            }
        }
        // fragments
        const int g = lane >> 4;
        short8 ah[2], al[2];
#pragma unroll
        for (int mt = 0; mt < 2; ++mt) {
            int row = wr * 32 + mt * 16 + (lane & 15);
            int s = g ^ (row & 3) ^ ((row >> 2) & 1);
            int bo = row * 64 + s * 16;
            ah[mt] = *(const short8*)((const char*)Ahi + bo);
            al[mt] = *(const short8*)((const char*)Alo + bo);
        }
        short8 bh[4], bl[4];
#pragma unroll
        for (int f = 0; f < 4; ++f) {
            int col = wc * 64 + f * 16 + (lane & 15);
            int s = g ^ (col & 3) ^ ((col >> 2) & 1);
            int bo = col * 64 + s * 16;
            bh[f] = *(const short8*)((const char*)Bhi + bo);
            bl[f] = *(const short8*)((const char*)Blo + bo);
        }
#pragma unroll
        for (int f = 0; f < 4; ++f) {
#pragma unroll
            for (int mt = 0; mt < 2; ++mt) {
                f32x4 a = acc[mt][f];
                a = __builtin_amdgcn_mfma_f32_16x16x32_bf16(ah[mt], bh[f], a, 0, 0, 0);
                a = __builtin_amdgcn_mfma_f32_16x16x32_bf16(al[mt], bh[f], a, 0, 0, 0);
                a = __builtin_amdgcn_mfma_f32_16x16x32_bf16(ah[mt], bl[f], a, 0, 0, 0);
                acc[mt][f] = a;
            }
        }
        __syncthreads();
    }

    // epilogue: h4 = relu(acc + lb2[col]); po += h4 * L3[col]; reduce over 16 col-lanes
    float po[2][4][2];
#pragma unroll
    for (int mt = 0; mt < 2; ++mt)
#pragma unroll
        for (int r2 = 0; r2 < 4; ++r2) { po[mt][r2][0] = 0.f; po[mt][r2][1] = 0.f; }
#pragma unroll
    for (int f = 0; f < 4; ++f) {
        int col = wcb + f * 16 + (lane & 15);
        float bb = lb2[col];
        float2 l3 = *(const float2*)(L3 + (size_t)col * 2);
#pragma unroll
        for (int mt = 0; mt < 2; ++mt)
#pragma unroll
            for (int r2 = 0; r2 < 4; ++r2) {
                float h4 = fmaxf(acc[mt][f][r2] + bb, 0.f);
                po[mt][r2][0] = fmaf(h4, l3.x, po[mt][r2][0]);
                po[mt][r2][1] = fmaf(h4, l3.y, po[mt][r2][1]);
            }
    }
#pragma unroll
    for (int ofs = 1; ofs <= 8; ofs <<= 1) {
#pragma unroll
        for (int mt = 0; mt < 2; ++mt)
#pragma unroll
            for (int r2 = 0; r2 < 4; ++r2) {
                po[mt][r2][0] += __shfl_xor(po[mt][r2][0], ofs, 64);
                po[mt][r2][1] += __shfl_xor(po[mt][r2][1], ofs, 64);
            }
    }
    if ((lane & 15) == 0) {
        const int g = lane >> 4;
#pragma unroll
        for (int mt = 0; mt < 2; ++mt)
#pragma unroll
            for (int r2 = 0; r2 < 4; ++r2) {
                int row_l = rb + wr * 32 + mt * 16 + g * 4 + r2;
                if (row_l < mh) {
                    atomicAdd(&out[(size_t)(base + row_l) * 2 + 0], po[mt][r2][0]);
                    atomicAdd(&out[(size_t)(base + row_l) * 2 + 1], po[mt][r2][1]);
                }
            }
    }
}

extern "C" void kernel_launch(void* const* d_in, const int* in_sizes, int n_in,
                              void* d_out, int out_size, void* d_ws, size_t ws_size,
                              hipStream_t stream) {
    const float* x   = (const float*)d_in[0];
    const int*   ei  = (const int*)d_in[1];
    const float* W1  = (const float*)d_in[2];
    const float* b1  = (const float*)d_in[3];
    const float* W2  = (const float*)d_in[4];
    const float* b2  = (const float*)d_in[5];
    const float* L1  = (const float*)d_in[6];
    const float* lb1 = (const float*)d_in[7];
    const float* L2w = (const float*)d_in[8];
    const float* lb2 = (const float*)d_in[9];
    const float* L3  = (const float*)d_in[10];
    const float* lb3 = (const float*)d_in[11];
    float* out = (float*)d_out;

    const int N = in_sizes[0] / 256;
    const int E = in_sizes[1] / 2;
    const int* rowp = ei;       // edge_index[0]
    const int* colp = ei + E;   // edge_index[1]

    const int mh0 = (N + 1) / 2;
    const int mh1 = N - mh0;
    const int nsb = (N + 255) / 256;                // scan blocks

    char* ws = (char*)d_ws;
    int*   deg    = (int*)ws;                       // N
    int*   cursor = deg + N;                        // N
    int*   offp   = cursor + N;                     // N
    float* dinv   = (float*)(offp + N);             // N
    int*   bsum   = (int*)(dinv + N);               // nsb
    int*   boffb  = bsum + 1024;                    // nsb (1024-padded)
    int*   nbr    = boffb + 1024;                   // E
    char*  bigbuf = (char*)(nbr + E);               // N*128*4*2 bytes, aliased
    float* t1s    = (float*)bigbuf;                 // N*128 floats
    float* h1     = t1s + (size_t)N * 128;          // N*128 floats
    short* h3hi   = (short*)bigbuf;                 // alias: mh*512 shorts (per half)
    short* h3lo   = h3hi + (size_t)mh0 * 512;       // alias
    float* t2s    = (float*)(bigbuf + (size_t)N * 128 * 4 * 2);   // N*12
    short* L2hi   = (short*)(t2s + (size_t)N * 12); // 512*512
    short* L2lo   = L2hi + 512 * 512;               // 512*512
    short* W1hi   = L2lo + 512 * 512;               // 256*128
    short* W1lo   = W1hi + 256 * 128;               // 256*128

    k_init  <<<(N + 255) / 256, 256, 0, stream>>>(deg, cursor, N);
    k_count <<<(E + 255) / 256, 256, 0, stream>>>(colp, deg, E);
    k_dinv  <<<(N + 255) / 256, 256, 0, stream>>>(deg, dinv, N);
    k_scanA <<<nsb, 256, 0, stream>>>(deg, bsum, N);
    k_scanB <<<1, 1024, 0, stream>>>(bsum, boffb, nsb);
    k_scanC <<<nsb, 256, 0, stream>>>(deg, boffb, offp, N);
    k_fill  <<<(E + 255) / 256, 256, 0, stream>>>(rowp, colp, offp, cursor, nbr, E);
    k_cvtL2 <<<512, 256, 0, stream>>>(L2w, L2hi, L2lo);
    k_cvtW1 <<<128, 256, 0, stream>>>(W1, W1hi, W1lo);

    k_gemm1   <<<(N + 63) / 64, 256, 0, stream>>>(x, W1hi, W1lo, dinv, t1s, N);
    k_gather1 <<<(N + 3) / 4, 256, 0, stream>>>(deg, offp, nbr, t1s, dinv, b1, h1, N);
    k_gemm2   <<<(N + 255) / 256, 256, 0, stream>>>(h1, W2, dinv, t2s, N);

    k_outinit <<<(2 * N + 255) / 256, 256, 0, stream>>>(out, lb3, 2 * N);

    int bases[2] = {0, mh0};
    int mhs[2]   = {mh0, mh1};
    for (int h = 0; h < 2; ++h) {
        int mh = mhs[h];
        if (mh <= 0) continue;
        int mt = (mh + 63) / 64;
        k_h3     <<<(mh + 15) / 16, 256, 0, stream>>>(deg, offp, nbr, t2s, dinv, b2,
                                                      L1, lb1, h3hi, h3lo, bases[h], mh);
        k_gemmL2 <<<mt * 4, 256, 0, stream>>>(h3hi, h3lo, L2hi, L2lo, lb2, L3,
                                              out, bases[h], mh);
    }
}